// Round 13
// baseline (306.768 us; speedup 1.0000x reference)
//
#include <hip/hip_runtime.h>
#include <math.h>

// B=128, S=256, G=8, CMAX=6, T=32, E=64, NH=4, dh=16, L=2, DFF=256, Z=3

typedef short bf16x8 __attribute__((ext_vector_type(8)));
typedef float f32x4 __attribute__((ext_vector_type(4)));

__device__ __forceinline__ unsigned short f2bf(float f) {
  unsigned u = __float_as_uint(f);
  u += 0x7fffu + ((u >> 16) & 1u);   // RNE
  return (unsigned short)(u >> 16);
}

__device__ __forceinline__ bf16x8 ldfrag(const unsigned short* p) {
  return *reinterpret_cast<const bf16x8*>(p);
}

__device__ __forceinline__ bool is_masked(const void* mask_, int flag, int idx) {
  return flag ? (((const unsigned char*)mask_)[idx] != 0)
              : (((const int*)mask_)[idx] != 0);
}

#define QSCALE 0.360673760f   // 0.25 * log2(e) — scores land in log2 domain

// Weight prep + PE table + mask-dtype detect + counter zeroing (one launch).
// wb layout (shorts): [0,24576) qkv (Wq pre-scaled QSCALE)  [24576,32768) wout
// [32768,65536) ff1  [65536,98304) ff2  [98304,108544) w1p[g][5][32][8]
// [108544,169984) w2p[g][3][64][40].  pe: float[256][64].
__global__ __launch_bounds__(256) void prep_all_kernel(
    const float* __restrict__ in_proj_w, const float* __restrict__ out_proj_w,
    const float* __restrict__ ff1_w, const float* __restrict__ ff2_w,
    const float* __restrict__ w1_, const float* __restrict__ w2_,
    unsigned short* __restrict__ wb, float* __restrict__ pe,
    const unsigned int* __restrict__ mw,
    int* __restrict__ flag, int* __restrict__ counts, int* __restrict__ lens) {
  int tid = threadIdx.x;
  int i = blockIdx.x * 256 + tid;
  if (i < 24576) {
    int rem = i % 12288, row = rem / 64;
    float v = in_proj_w[i];
    if (row < 64) v *= QSCALE;
    wb[i] = f2bf(v);
  } else if (i < 32768) {
    wb[i] = f2bf(out_proj_w[i - 24576]);
  } else if (i < 65536) {
    wb[i] = f2bf(ff1_w[i - 32768]);
  } else if (i < 98304) {
    wb[i] = f2bf(ff2_w[i - 65536]);
  } else if (i < 108544) {
    int j = i - 98304;
    int g = j / 1280, rem = j % 1280;
    int k = rem >> 8, rest = rem & 255, oc = rest >> 3, ic = rest & 7;
    wb[i] = (ic < 6) ? f2bf(w1_[g * 960 + oc * 30 + ic * 5 + k]) : 0;
  } else if (i < 169984) {
    int j = i - 108544;
    int g = j / 7680, rem = j % 7680;
    int k = rem / 2560, rest = rem % 2560, e = rest / 40, ic = rest % 40;
    wb[i] = (ic < 32) ? f2bf(w2_[g * 6144 + e * 96 + ic * 3 + k]) : 0;
  } else if (i < 186368) {
    int j = i - 169984;
    int s = j >> 6, e = j & 63;
    float div = __expf(-(float)(e & ~1) * (9.21034037f / 64.f));
    float angle = (float)s * div;
    pe[j] = (e & 1) ? cosf(angle) : sinf(angle);
  }
  if (blockIdx.x == 0) {
    __shared__ int sh;
    if (tid == 0) sh = 0;
    __syncthreads();
    int bad = 0;
    for (int k = tid; k < 8192; k += 256)
      if (mw[k] > 1u) bad = 1;
    if (bad) atomicOr(&sh, 1);
    if (tid < 8) counts[tid] = 0;
    if (tid < 128) lens[tid] = 0;
    __syncthreads();
    if (tid == 0) *flag = sh;
  }
}

// Base embedding (fp32 + bf16 mirror) from PE table; blocks < 128 also bin
// active tokens by shank id. Conv overwrites active rows later.
__global__ __launch_bounds__(256) void init_bin_kernel(
    const int* __restrict__ sid, const float* __restrict__ shank_emb,
    const float* __restrict__ pe,
    const void* __restrict__ mask_, const int* __restrict__ flagp,
    int* __restrict__ counts, int* __restrict__ lens, int* __restrict__ idxbuf,
    float* __restrict__ hout, unsigned short* __restrict__ hb) {
  __shared__ int lcnt[8];
  __shared__ int lbase[8];
  int tid = threadIdx.x;
  int i = blockIdx.x * 256 + tid;
  {
    int n = i >> 6, e = i & 63;
    int g = sid[n];
    float v = shank_emb[g * 64 + e] + pe[i & 16383];
    hout[i] = v;
    hb[i] = f2bf(v);
  }
  if (blockIdx.x < 128) {
    int b = blockIdx.x;
    int n = b * 256 + tid;
    int flag = *flagp;
    bool act = !is_masked(mask_, flag, n);
    int g = act ? sid[n] : 0;
    if (tid < 8) lcnt[tid] = 0;
    __syncthreads();
    int pos = 0;
    if (act) pos = atomicAdd(&lcnt[g], 1);
    __syncthreads();
    if (tid < 8) lbase[tid] = atomicAdd(&counts[tid], lcnt[tid]);
    if (tid == 0)
      lens[b] = lcnt[0] + lcnt[1] + lcnt[2] + lcnt[3] +
                lcnt[4] + lcnt[5] + lcnt[6] + lcnt[7];
    __syncthreads();
    if (act) idxbuf[g * 32768 + lbase[g] + pos] = n;
  }
}

// Conv encoder via bf16 MFMA — wave-independent, software-pipelined, PE from
// table (no per-token trig).
__global__ __launch_bounds__(256) void conv_mfma_kernel(
    const int* __restrict__ idxbuf, const int* __restrict__ counts,
    const float* __restrict__ wav, const unsigned short* __restrict__ wb,
    const float* __restrict__ b1_, const float* __restrict__ b2_,
    const float* __restrict__ shank_emb, const float* __restrict__ pe,
    float* __restrict__ hout, unsigned short* __restrict__ hb) {
  __shared__ __align__(16) unsigned short w1f[5][32][8];
  __shared__ __align__(16) unsigned short w2f[3][64][40];
  __shared__ float b1s[32];
  __shared__ float b2s[64];
  __shared__ __align__(16) unsigned short xw[4][36][8];
  __shared__ __align__(16) unsigned short h1w[4][34][40];
  int g = blockIdx.x & 7, bib = blockIdx.x >> 3;
  int tid = threadIdx.x;
  int wvx = tid >> 6, lane = tid & 63, quad = lane >> 4, l15 = lane & 15;
  {
    const uint4* s1 = (const uint4*)(wb + 98304 + g * 1280);
    uint4* d1 = (uint4*)&w1f[0][0][0];
    for (int i = tid; i < 160; i += 256) d1[i] = s1[i];
    const uint4* s2 = (const uint4*)(wb + 108544 + g * 7680);
    uint4* d2 = (uint4*)&w2f[0][0][0];
    for (int i = tid; i < 960; i += 256) d2[i] = s2[i];
  }
  if (tid < 32) b1s[tid] = b1_[g * 32 + tid];
  if (tid < 64) b2s[tid] = b2_[g * 64 + tid];
  {
    unsigned int* xz = (unsigned int*)&xw[wvx][0][0];
    for (int i = lane; i < 144; i += 64) xz[i] = 0;
    unsigned int* hz0 = (unsigned int*)&h1w[wvx][0][0];
    unsigned int* hz1 = (unsigned int*)&h1w[wvx][33][0];
    if (lane < 20) hz0[lane] = 0;
    else if (lane < 40) hz1[lane - 20] = 0;
  }
  __syncthreads();
  bf16x8 zf = {0, 0, 0, 0, 0, 0, 0, 0};
  bf16x8 bf1[2], bf1k4[2], bf2[3][4];
#pragma unroll
  for (int nt = 0; nt < 2; nt++) {
    bf1[nt] = ldfrag(&w1f[quad][nt * 16 + l15][0]);
    bf1k4[nt] = (quad == 0) ? ldfrag(&w1f[4][nt * 16 + l15][0]) : zf;
  }
#pragma unroll
  for (int k = 0; k < 3; k++)
#pragma unroll
    for (int nt = 0; nt < 4; nt++)
      bf2[k][nt] = ldfrag(&w2f[k][nt * 16 + l15][quad * 8]);
  float b1v0 = b1s[l15], b1v1 = b1s[16 + l15];
  float shank = shank_emb[g * 64 + lane];
  int cnt = counts[g];
  int ic_w = lane >> 3, t0_w = (lane & 7) * 4;
  int ti = bib * 4 + wvx;
  int n = 0;
  float4 v = make_float4(0.f, 0.f, 0.f, 0.f);
  if (ti < cnt) {
    n = idxbuf[g * 32768 + ti];
    if (lane < 48) v = *(const float4*)&wav[n * 192 + lane * 4];
  }
  while (ti < cnt) {
    int tn = ti + 640;
    int n2 = 0;
    float4 v2 = make_float4(0.f, 0.f, 0.f, 0.f);
    if (tn < cnt) {
      n2 = idxbuf[g * 32768 + tn];
      if (lane < 48) v2 = *(const float4*)&wav[n2 * 192 + lane * 4];
    }
    float pev = pe[(n & 255) * 64 + lane];
    if (lane < 48) {
      xw[wvx][t0_w + 2][ic_w] = f2bf(v.x);
      xw[wvx][t0_w + 3][ic_w] = f2bf(v.y);
      xw[wvx][t0_w + 4][ic_w] = f2bf(v.z);
      xw[wvx][t0_w + 5][ic_w] = f2bf(v.w);
    }
    f32x4 c1[2][2];
#pragma unroll
    for (int mt = 0; mt < 2; mt++) {
      c1[mt][0] = (f32x4){b1v0, b1v0, b1v0, b1v0};
      c1[mt][1] = (f32x4){b1v1, b1v1, b1v1, b1v1};
    }
#pragma unroll
    for (int mt = 0; mt < 2; mt++) {
      bf16x8 afm = ldfrag(&xw[wvx][mt * 16 + l15 + quad][0]);
      bf16x8 af4 = (quad == 0) ? ldfrag(&xw[wvx][mt * 16 + l15 + 4][0]) : zf;
#pragma unroll
      for (int nt = 0; nt < 2; nt++) {
        c1[mt][nt] = __builtin_amdgcn_mfma_f32_16x16x32_bf16(afm, bf1[nt], c1[mt][nt], 0, 0, 0);
        c1[mt][nt] = __builtin_amdgcn_mfma_f32_16x16x32_bf16(af4, bf1k4[nt], c1[mt][nt], 0, 0, 0);
      }
    }
#pragma unroll
    for (int mt = 0; mt < 2; mt++)
#pragma unroll
      for (int nt = 0; nt < 2; nt++)
#pragma unroll
        for (int r = 0; r < 4; r++) {
          int t = mt * 16 + quad * 4 + r;
          h1w[wvx][t + 1][nt * 16 + l15] = f2bf(fmaxf(c1[mt][nt][r], 0.f));
        }
    f32x4 c2[2][4];
#pragma unroll
    for (int mt = 0; mt < 2; mt++)
#pragma unroll
      for (int nt = 0; nt < 4; nt++) {
        float bv = b2s[nt * 16 + l15];
        c2[mt][nt] = (f32x4){bv, bv, bv, bv};
      }
#pragma unroll
    for (int k = 0; k < 3; k++)
#pragma unroll
      for (int mt = 0; mt < 2; mt++) {
        bf16x8 af = ldfrag(&h1w[wvx][mt * 16 + l15 + k][quad * 8]);
#pragma unroll
        for (int nt = 0; nt < 4; nt++)
          c2[mt][nt] = __builtin_amdgcn_mfma_f32_16x16x32_bf16(af, bf2[k][nt], c2[mt][nt], 0, 0, 0);
      }
    float sums[4];
#pragma unroll
    for (int nt = 0; nt < 4; nt++) {
      float s = 0.f;
#pragma unroll
      for (int mt = 0; mt < 2; mt++)
#pragma unroll
        for (int r = 0; r < 4; r++) s += fmaxf(c2[mt][nt][r], 0.f);
      s += __shfl_xor(s, 16);
      s += __shfl_xor(s, 32);
      sums[nt] = s;
    }
    float t0 = __shfl(sums[0], l15);
    float t1 = __shfl(sums[1], l15);
    float t2 = __shfl(sums[2], l15);
    float t3 = __shfl(sums[3], l15);
    float val = (quad == 0) ? t0 : (quad == 1) ? t1 : (quad == 2) ? t2 : t3;
    float hv = val * (1.f / 32.f) + shank + pev;
    hout[(size_t)n * 64 + lane] = hv;
    hb[(size_t)n * 64 + lane] = f2bf(hv);
    ti = tn; n = n2; v = v2;
  }
}

// Fused qkv + flash attention. Scores in log2 domain (Wq pre-scaled by
// 0.25*log2e) -> softmax uses raw exp2.
__global__ __launch_bounds__(256) void attn_fused_kernel(
    const unsigned short* __restrict__ hb, const unsigned short* __restrict__ wqkv,
    const float* __restrict__ bqkv, const int* __restrict__ lens,
    unsigned short* __restrict__ obuf) {
  __shared__ __align__(16) unsigned short qs[256][24];
  __shared__ __align__(16) unsigned short kst[256][24];
  __shared__ __align__(16) unsigned short vT[16][264];
  __shared__ __align__(16) unsigned short pw[4][16][264];
  int bh = blockIdx.x;
  int b_ = bh >> 2, hd = bh & 3;
  int tid = threadIdx.x;
  int wvx = tid >> 6, lane = tid & 63, quad = lane >> 4, l15 = lane & 15;
  int len = lens[b_];
  const unsigned short* hbb = hb + (size_t)b_ * 256 * 64;
  const unsigned short* wq = wqkv + (hd * 16) * 64;        // pre-scaled QSCALE
  const unsigned short* wk = wqkv + (64 + hd * 16) * 64;
  const unsigned short* wv = wqkv + (128 + hd * 16) * 64;
  float bq_ = QSCALE * bqkv[hd * 16 + l15];
  float bk_ = bqkv[64 + hd * 16 + l15];
  f32x4 bv_;
#pragma unroll
  for (int r = 0; r < 4; r++) bv_[r] = bqkv[128 + hd * 16 + quad * 4 + r];
#pragma unroll
  for (int t4 = 0; t4 < 4; t4++) {
    int tile = wvx * 4 + t4;
    f32x4 aq = (f32x4){bq_, bq_, bq_, bq_};
    f32x4 ak = (f32x4){bk_, bk_, bk_, bk_};
    f32x4 av = bv_;
#pragma unroll
    for (int ks = 0; ks < 64; ks += 32) {
      bf16x8 af = ldfrag(hbb + (tile * 16 + l15) * 64 + ks + quad * 8);
      aq = __builtin_amdgcn_mfma_f32_16x16x32_bf16(af, ldfrag(wq + l15 * 64 + ks + quad * 8), aq, 0, 0, 0);
      ak = __builtin_amdgcn_mfma_f32_16x16x32_bf16(af, ldfrag(wk + l15 * 64 + ks + quad * 8), ak, 0, 0, 0);
      av = __builtin_amdgcn_mfma_f32_16x16x32_bf16(ldfrag(wv + l15 * 64 + ks + quad * 8), af, av, 0, 0, 0);
    }
#pragma unroll
    for (int r = 0; r < 4; r++) {
      qs[tile * 16 + quad * 4 + r][l15] = f2bf(aq[r]);
      kst[tile * 16 + quad * 4 + r][l15] = f2bf(ak[r]);
      vT[quad * 4 + r][tile * 16 + l15] = f2bf(av[r]);
    }
  }
  __syncthreads();
  bf16x8 zf = {0, 0, 0, 0, 0, 0, 0, 0};
  f32x4 zero = {0.f, 0.f, 0.f, 0.f};
#pragma unroll 1
  for (int j = 0; j < 4; j++) {
    int qt = wvx * 4 + j;
    bf16x8 bq = (quad < 2) ? ldfrag(&qs[qt * 16 + l15][quad * 8]) : zf;
    f32x4 s[16];
#pragma unroll
    for (int t = 0; t < 16; t++) {
      bf16x8 ak = (quad < 2) ? ldfrag(&kst[t * 16 + l15][quad * 8]) : zf;
      s[t] = __builtin_amdgcn_mfma_f32_16x16x32_bf16(ak, bq, zero, 0, 0, 0);
    }
    float mx = -1e30f;
#pragma unroll
    for (int t = 0; t < 16; t++)
#pragma unroll
      for (int r = 0; r < 4; r++) {
        int key = t * 16 + quad * 4 + r;
        float v = (key < len) ? s[t][r] : -1e30f;
        s[t][r] = v;
        mx = fmaxf(mx, v);
      }
    mx = fmaxf(mx, __shfl_xor(mx, 16));
    mx = fmaxf(mx, __shfl_xor(mx, 32));
    float sum = 0.f;
#pragma unroll
    for (int t = 0; t < 16; t++)
#pragma unroll
      for (int r = 0; r < 4; r++) {
        float p = exp2f(s[t][r] - mx);   // scores already in log2 domain
        s[t][r] = p;
        sum += p;
      }
    sum += __shfl_xor(sum, 16);
    sum += __shfl_xor(sum, 32);
#pragma unroll
    for (int t = 0; t < 16; t++) {
      short4 pp;
      pp.x = (short)f2bf(s[t][0]); pp.y = (short)f2bf(s[t][1]);
      pp.z = (short)f2bf(s[t][2]); pp.w = (short)f2bf(s[t][3]);
      *(short4*)&pw[wvx][l15][t * 16 + quad * 4] = pp;
    }
    f32x4 acc = zero;
#pragma unroll
    for (int c = 0; c < 8; c++) {
      bf16x8 avv = ldfrag(&vT[l15][c * 32 + quad * 8]);
      bf16x8 bp = ldfrag(&pw[wvx][l15][c * 32 + quad * 8]);
      acc = __builtin_amdgcn_mfma_f32_16x16x32_bf16(avv, bp, acc, 0, 0, 0);
    }
    float inv = 1.f / sum;
    short4 w;
    w.x = (short)f2bf(acc[0] * inv); w.y = (short)f2bf(acc[1] * inv);
    w.z = (short)f2bf(acc[2] * inv); w.w = (short)f2bf(acc[3] * inv);
    *(short4*)&obuf[(size_t)(b_ * 256 + qt * 16 + l15) * 64 + hd * 16 + quad * 4] = w;
  }
}

// Fused row-local trio — zero barriers, zero weight staging.
__global__ __launch_bounds__(256) void fused_rl_kernel(
    const unsigned short* __restrict__ obuf, float* __restrict__ H,
    unsigned short* __restrict__ Hb,
    const unsigned short* __restrict__ wout, const float* __restrict__ bout,
    const float* __restrict__ ln1g, const float* __restrict__ ln1b,
    const unsigned short* __restrict__ wff1, const float* __restrict__ bff1,
    const unsigned short* __restrict__ wff2, const float* __restrict__ bff2,
    const float* __restrict__ ln2g, const float* __restrict__ ln2b) {
  __shared__ __align__(16) unsigned short h1b[64][72];
  __shared__ __align__(16) unsigned short ffa[64][264];
  int m0 = blockIdx.x * 64;
  int tid = threadIdx.x;
  int wvx = tid >> 6, lane = tid & 63, quad = lane >> 4, l15 = lane & 15;
  int lr = wvx * 16 + quad * 4;
  f32x4 acc[4];
#pragma unroll
  for (int nt = 0; nt < 4; nt++) {
    float b = bout[nt * 16 + l15];
    acc[nt] = (f32x4){b, b, b, b};
  }
#pragma unroll
  for (int ks = 0; ks < 64; ks += 32) {
    bf16x8 af = ldfrag(obuf + (size_t)(m0 + wvx * 16 + l15) * 64 + ks + quad * 8);
#pragma unroll
    for (int nt = 0; nt < 4; nt++) {
      bf16x8 bfr = ldfrag(wout + (nt * 16 + l15) * 64 + ks + quad * 8);
      acc[nt] = __builtin_amdgcn_mfma_f32_16x16x32_bf16(af, bfr, acc[nt], 0, 0, 0);
    }
  }
  float h1reg[4][4];
#pragma unroll
  for (int r = 0; r < 4; r++) {
    float rv[4];
    float s = 0.f;
#pragma unroll
    for (int nt = 0; nt < 4; nt++) {
      float v = acc[nt][r] + H[(size_t)(m0 + lr + r) * 64 + nt * 16 + l15];
      rv[nt] = v; s += v;
    }
    s += __shfl_xor(s, 1); s += __shfl_xor(s, 2);
    s += __shfl_xor(s, 4); s += __shfl_xor(s, 8);
    float mean = s * (1.f / 64.f);
    float vsum = 0.f;
#pragma unroll
    for (int nt = 0; nt < 4; nt++) { rv[nt] -= mean; vsum += rv[nt] * rv[nt]; }
    vsum += __shfl_xor(vsum, 1); vsum += __shfl_xor(vsum, 2);
    vsum += __shfl_xor(vsum, 4); vsum += __shfl_xor(vsum, 8);
    float inv = rsqrtf(vsum * (1.f / 64.f) + 1e-5f);
#pragma unroll
    for (int nt = 0; nt < 4; nt++) {
      int col = nt * 16 + l15;
      float hv = rv[nt] * inv * ln1g[col] + ln1b[col];
      h1reg[r][nt] = hv;
      h1b[lr + r][col] = f2bf(hv);
    }
  }
  f32x4 a2[16];
#pragma unroll
  for (int nt = 0; nt < 16; nt++) {
    float b = bff1[nt * 16 + l15];
    a2[nt] = (f32x4){b, b, b, b};
  }
#pragma unroll
  for (int ks = 0; ks < 64; ks += 32) {
    bf16x8 af = ldfrag(&h1b[wvx * 16 + l15][ks + quad * 8]);
#pragma unroll
    for (int nt = 0; nt < 16; nt++) {
      bf16x8 bfr = ldfrag(wff1 + (nt * 16 + l15) * 64 + ks + quad * 8);
      a2[nt] = __builtin_amdgcn_mfma_f32_16x16x32_bf16(af, bfr, a2[nt], 0, 0, 0);
    }
  }
#pragma unroll
  for (int nt = 0; nt < 16; nt++)
#pragma unroll
    for (int r = 0; r < 4; r++)
      ffa[lr + r][nt * 16 + l15] = f2bf(fmaxf(a2[nt][r], 0.f));
#pragma unroll
  for (int nt = 0; nt < 4; nt++) {
    float b = bff2[nt * 16 + l15];
    acc[nt] = (f32x4){b, b, b, b};
  }
#pragma unroll
  for (int ks = 0; ks < 256; ks += 32) {
    bf16x8 af = ldfrag(&ffa[wvx * 16 + l15][ks + quad * 8]);
#pragma unroll
    for (int nt = 0; nt < 4; nt++) {
      bf16x8 bfr = ldfrag(wff2 + (nt * 16 + l15) * 256 + ks + quad * 8);
      acc[nt] = __builtin_amdgcn_mfma_f32_16x16x32_bf16(af, bfr, acc[nt], 0, 0, 0);
    }
  }
#pragma unroll
  for (int r = 0; r < 4; r++) {
    float rv[4];
    float s = 0.f;
#pragma unroll
    for (int nt = 0; nt < 4; nt++) {
      float v = acc[nt][r] + h1reg[r][nt];
      rv[nt] = v; s += v;
    }
    s += __shfl_xor(s, 1); s += __shfl_xor(s, 2);
    s += __shfl_xor(s, 4); s += __shfl_xor(s, 8);
    float mean = s * (1.f / 64.f);
    float vsum = 0.f;
#pragma unroll
    for (int nt = 0; nt < 4; nt++) { rv[nt] -= mean; vsum += rv[nt] * rv[nt]; }
    vsum += __shfl_xor(vsum, 1); vsum += __shfl_xor(vsum, 2);
    vsum += __shfl_xor(vsum, 4); vsum += __shfl_xor(vsum, 8);
    float inv = rsqrtf(vsum * (1.f / 64.f) + 1e-5f);
#pragma unroll
    for (int nt = 0; nt < 4; nt++) {
      int col = nt * 16 + l15;
      float hv = rv[nt] * inv * ln2g[col] + ln2b[col];
      H[(size_t)(m0 + lr + r) * 64 + col] = hv;
      Hb[(size_t)(m0 + lr + r) * 64 + col] = f2bf(hv);
    }
  }
}

// Fused masked mean pool + all heads.
__global__ __launch_bounds__(256) void pool_heads_kernel(
    const float* __restrict__ h, const int* __restrict__ lens,
    const float* __restrict__ cls_w1, const float* __restrict__ cls_b1,
    const float* __restrict__ cls_w2, const float* __restrict__ cls_b2,
    const float* __restrict__ mu_w1, const float* __restrict__ mu_b1,
    const float* __restrict__ mu_w2, const float* __restrict__ mu_b2,
    const float* __restrict__ ls_w1, const float* __restrict__ ls_b1,
    const float* __restrict__ ls_w2, const float* __restrict__ ls_b2,
    const float* __restrict__ d_w1, const float* __restrict__ d_b1,
    const float* __restrict__ d_w2, const float* __restrict__ d_b2,
    float* __restrict__ out) {
  __shared__ float ps[4][64];
  __shared__ float p[64];
  __shared__ float t1[64];
  int b = blockIdx.x, tid = threadIdx.x;
  int e = tid & 63, sp = tid >> 6;
  int len = lens[b];
  {
    float sum = 0.f;
    int send = min(sp * 64 + 64, len);
    for (int s = sp * 64; s < send; s++) sum += h[(size_t)(b * 256 + s) * 64 + e];
    ps[sp][e] = sum;
  }
  __syncthreads();
  if (sp == 0)
    p[e] = (ps[0][e] + ps[1][e] + ps[2][e] + ps[3][e]) / ((float)len + 1e-8f);
  __syncthreads();
  if (tid < 64) {
    float a = cls_b1[tid];
    for (int j = 0; j < 64; j++) a += p[j] * cls_w1[tid * 64 + j];
    t1[tid] = fmaxf(a, 0.f);
  }
  __syncthreads();
  if (tid < 3) {
    float a2 = cls_b2[tid];
    for (int j = 0; j < 64; j++) a2 += t1[j] * cls_w2[tid * 64 + j];
    out[b * 16 + tid] = a2;
  }
  for (int z = 0; z < 3; z++) {
    __syncthreads();
    if (tid < 64) {
      float a = mu_b1[z * 64 + tid];
      for (int j = 0; j < 64; j++) a += p[j] * mu_w1[(z * 64 + tid) * 64 + j];
      t1[tid] = fmaxf(a, 0.f);
    }
    __syncthreads();
    if (tid < 2) {
      float a2 = mu_b2[z * 2 + tid];
      for (int j = 0; j < 64; j++) a2 += t1[j] * mu_w2[(z * 2 + tid) * 64 + j];
      out[b * 16 + 3 + z * 2 + tid] = a2;
    }
    __syncthreads();
    if (tid < 64) {
      float a = ls_b1[z * 64 + tid];
      for (int j = 0; j < 64; j++) a += p[j] * ls_w1[(z * 64 + tid) * 64 + j];
      t1[tid] = fmaxf(a, 0.f);
    }
    __syncthreads();
    if (tid < 2) {
      float a2 = ls_b2[z * 2 + tid];
      for (int j = 0; j < 64; j++) a2 += t1[j] * ls_w2[(z * 2 + tid) * 64 + j];
      out[b * 16 + 9 + z * 2 + tid] = __expf(a2);
    }
  }
  __syncthreads();
  if (tid < 64) {
    float a = d_b1[tid];
    for (int j = 0; j < 64; j++) a += p[j] * d_w1[tid * 64 + j];
    t1[tid] = fmaxf(a, 0.f);
  }
  __syncthreads();
  if (tid == 0) {
    float a2 = d_b2[0];
    for (int j = 0; j < 64; j++) a2 += t1[j] * d_w2[j];
    out[b * 16 + 15] = 1.f / (1.f + __expf(-a2));
  }
}

extern "C" void kernel_launch(void* const* d_in, const int* in_sizes, int n_in,
                              void* d_out, int out_size, void* d_ws, size_t ws_size,
                              hipStream_t stream) {
  const float* wav       = (const float*)d_in[0];
  const int*   sid       = (const int*)d_in[1];
  const void*  mask      = d_in[2];
  const float* conv1_w   = (const float*)d_in[3];
  const float* conv1_b   = (const float*)d_in[4];
  const float* conv2_w   = (const float*)d_in[5];
  const float* conv2_b   = (const float*)d_in[6];
  const float* shank_emb = (const float*)d_in[7];
  const float* in_proj_w = (const float*)d_in[8];
  const float* in_proj_b = (const float*)d_in[9];
  const float* out_proj_w= (const float*)d_in[10];
  const float* out_proj_b= (const float*)d_in[11];
  const float* ln1_g     = (const float*)d_in[12];
  const float* ln1_b     = (const float*)d_in[13];
  const float* ff1_w     = (const float*)d_in[14];
  const float* ff1_b     = (const float*)d_in[15];
  const float* ff2_w     = (const float*)d_in[16];
  const float* ff2_b     = (const float*)d_in[17];
  const float* ln2_g     = (const float*)d_in[18];
  const float* ln2_b     = (const float*)d_in[19];
  const float* cls_w1    = (const float*)d_in[20];
  const float* cls_b1    = (const float*)d_in[21];
  const float* cls_w2    = (const float*)d_in[22];
  const float* cls_b2    = (const float*)d_in[23];
  const float* mu_w1     = (const float*)d_in[24];
  const float* mu_b1     = (const float*)d_in[25];
  const float* mu_w2     = (const float*)d_in[26];
  const float* mu_b2     = (const float*)d_in[27];
  const float* ls_w1     = (const float*)d_in[28];
  const float* ls_b1     = (const float*)d_in[29];
  const float* ls_w2     = (const float*)d_in[30];
  const float* ls_b2     = (const float*)d_in[31];
  const float* d_w1      = (const float*)d_in[32];
  const float* d_b1      = (const float*)d_in[33];
  const float* d_w2      = (const float*)d_in[34];
  const float* d_b2      = (const float*)d_in[35];
  float* out = (float*)d_out;

  float* ws = (float*)d_ws;
  float*          h     = ws;                                  // [32768,64] fp32
  unsigned short* hb    = (unsigned short*)(ws + 2097152);     // bf16 mirror
  unsigned short* obufb = (unsigned short*)(ws + 3145728);     // attn out bf16
  unsigned short* wb    = (unsigned short*)(ws + 4194304);     // prepped weights
  float*          pet   = ws + 8388608;                        // PE[256][64]
  int*   ip     = (int*)(ws + 10493952);
  int*   flag   = ip;
  int*   counts = ip + 8;
  int*   lens   = ip + 16;
  int*   idxbuf = ip + 144;

  prep_all_kernel<<<728, 256, 0, stream>>>(in_proj_w, out_proj_w, ff1_w, ff2_w,
                                           conv1_w, conv2_w, wb, pet,
                                           (const unsigned int*)mask, flag, counts, lens);
  init_bin_kernel<<<8192, 256, 0, stream>>>(sid, shank_emb, pet, mask, flag, counts,
                                            lens, idxbuf, h, hb);
  conv_mfma_kernel<<<1280, 256, 0, stream>>>(idxbuf, counts, wav, wb, conv1_b, conv2_b,
                                             shank_emb, pet, h, hb);
  for (int l = 0; l < 2; l++) {
    attn_fused_kernel<<<512, 256, 0, stream>>>(hb, wb + l * 12288,
                                               in_proj_b + l * 192, lens, obufb);
    fused_rl_kernel<<<512, 256, 0, stream>>>(
        obufb, h, hb,
        wb + 24576 + l * 4096, out_proj_b + l * 64,
        ln1_g + l * 64, ln1_b + l * 64,
        wb + 32768 + l * 16384, ff1_b + l * 256,
        wb + 65536 + l * 16384, ff2_b + l * 64,
        ln2_g + l * 64, ln2_b + l * 64);
  }
  pool_heads_kernel<<<128, 256, 0, stream>>>(h, lens, cls_w1, cls_b1, cls_w2, cls_b2,
                                             mu_w1, mu_b1, mu_w2, mu_b2,
                                             ls_w1, ls_b1, ls_w2, ls_b2,
                                             d_w1, d_b1, d_w2, d_b2, out);
}